// Round 5
// baseline (98.937 us; speedup 1.0000x reference)
//
#include <hip/hip_runtime.h>
#include <hip/hip_bf16.h>

#define BATCH 512
#define DIM 256
#define NT 512
#define DEPTH 6
#define UNITS 3
#define NL 64
#define COLS (NT * DEPTH)  // 3072
#define KMAX 32            // padded sparse entries per column (zero-filled)

// ws layout (floats):
//   val4 [DEPTH][8][NT] float4   98304 f   packed sparse values (4/group)
//   idx4 [DEPTH][8][NT] uint     24576 f   packed sparse indices (4x u8)
//   cnt  [DEPTH][NT] int          3072 f

// ---- Kernel 1: sparsemax (Newton) + packed compaction ---------------------
// 192 blocks x 512 thr. Block loads a 256-row x 16-col logits tile into LDS
// (coalesced global, 2-way-free LDS writes, conflict-free column reads),
// then each of 8 waves runs Newton sparsemax on 2 columns.
__global__ __launch_bounds__(512) void k_sparse(
    const float* __restrict__ logits, float4* __restrict__ val4,
    unsigned int* __restrict__ idx4, int* __restrict__ cnt) {
  const int tid = threadIdx.x;
  const int c0 = blockIdx.x * 16;
  __shared__ float tile[16][260];  // [col][row], stride 260: banks +4 per col
#pragma unroll
  for (int it = 0; it < 8; ++it) {
    int e = it * 512 + tid;  // 0..4095
    int r = e >> 4, c = e & 15;
    tile[c][r] = logits[r * COLS + c0 + c];  // 64B-coalesced per 16 lanes
  }
  __syncthreads();

  const int wv = tid >> 6, lane = tid & 63;
  float* vbase = (float*)val4;
  unsigned char* ibase = (unsigned char*)idx4;

#pragma unroll
  for (int q = 0; q < 2; ++q) {
    const int cl = wv * 2 + q;  // 0..15
    const int col = c0 + cl;    // col = n*DEPTH + d
    const int n = col / DEPTH, d = col % DEPTH;

    float z[4];
#pragma unroll
    for (int j = 0; j < 4; ++j) z[j] = tile[cl][j * 64 + lane];  // no conflict

    float m = fmaxf(fmaxf(z[0], z[1]), fmaxf(z[2], z[3]));
#pragma unroll
    for (int o = 32; o > 0; o >>= 1) m = fmaxf(m, __shfl_xor(m, o, 64));

    // Newton on g(tau)=sum relu(z-tau)-1: convex piecewise-linear; from
    // tau0=max-1 (g>=0) converges monotonically, exact in final segment.
    float tau = m - 1.0f;
    for (int itn = 0; itn < 16; ++itn) {
      float s = 0.0f, k = 0.0f;
#pragma unroll
      for (int j = 0; j < 4; ++j) {
        float dd = z[j] - tau;
        if (dd > 0.0f) { s += dd; k += 1.0f; }
      }
#pragma unroll
      for (int o = 32; o > 0; o >>= 1) {
        s += __shfl_xor(s, o, 64);
        k += __shfl_xor(k, o, 64);
      }
      float delta = (s - 1.0f) / k;  // k>=1 always (tau < max)
      tau += delta;
      if (fabsf(delta) < 1e-7f) break;  // wave-uniform (s,k fully reduced)
    }

    // compact nonzeros into SoA groups of 4 (order-free: consumer sums)
    int base = 0;
#pragma unroll
    for (int j = 0; j < 4; ++j) {
      bool nz = z[j] > tau;
      unsigned long long mk = __ballot(nz);
      int pos = base + __popcll(mk & ((1ull << lane) - 1ull));
      if (nz && pos < KMAX) {
        int slot = ((d * 8 + (pos >> 2)) * NT + n) * 4 + (pos & 3);
        vbase[slot] = z[j] - tau;
        ibase[slot] = (unsigned char)(j * 64 + lane);
      }
      base += __popcll(mk);
    }
    const int cc = min(base, KMAX);
    if (lane >= cc && lane < KMAX) {  // zero-fill padding
      int slot = ((d * 8 + (lane >> 2)) * NT + n) * 4 + (lane & 3);
      vbase[slot] = 0.0f;
      ibase[slot] = 0;
    }
    if (lane == 0) cnt[d * NT + n] = cc;
  }
}

// ---- Kernel 2: sparse fv -> gates -> leaves -> output ---------------------
// 1024 blocks x 256 thr: block = 64 trees x 4 batch rows, 1 row/thread.
// Response slab for the block's 64 trees staged in LDS (conflict-free
// epilogue reads); x rows in LDS; blockIdx&7 = tree-tile -> XCD L2 locality.
__global__ __launch_bounds__(256) void k_forest5(
    const float* __restrict__ x, const float4* __restrict__ val4,
    const unsigned int* __restrict__ idx4, const int* __restrict__ cnt,
    const float* __restrict__ thr, const float* __restrict__ ltemp,
    const float* __restrict__ resp, float* __restrict__ out) {
  const int tid = threadIdx.x;
  const int nloc = tid & 63, bg = tid >> 6;
  const int tt = blockIdx.x & 7, bt = blockIdx.x >> 3;  // bt 0..127
  const int n = tt * 64 + nloc, n0 = tt * 64;
  const int b = bt * 4 + bg;

  __shared__ float xl[4 * DIM];          // 4 batch rows
  __shared__ float rsp[UNITS][NL][65];   // [u][c][nloc], pad -> stride 65
#pragma unroll
  for (int k2 = 0; k2 < 4; ++k2)
    xl[k2 * 256 + tid] = x[(bt * 4 + k2) * DIM + tid];
  for (int k2 = 0; k2 < 48; ++k2) {
    int e = k2 * 256 + tid;              // 0..12287, coalesced global read
    int nl = e / 192, rem = e - nl * 192;
    rsp[rem >> 6][rem & 63][nl] = resp[n0 * 192 + e];
  }
  __syncthreads();

  const float* xr = &xl[bg * DIM];
  float fv[DEPTH];
#pragma unroll
  for (int d = 0; d < DEPTH; ++d) fv[d] = 0.0f;

#pragma unroll
  for (int d = 0; d < DEPTH; ++d) {
    int mc = cnt[d * NT + n];  // coalesced over lanes
#pragma unroll
    for (int o = 32; o > 0; o >>= 1) mc = max(mc, __shfl_xor(mc, o, 64));
    const int nq = (mc + 3) >> 2;  // wave-uniform group count
#pragma unroll
    for (int jq = 0; jq < 8; ++jq) {
      if (jq < nq) {  // uniform branch, independent of load data
        float4 v = val4[(d * 8 + jq) * NT + n];         // coalesced 16B
        unsigned int ip = idx4[(d * 8 + jq) * NT + n];  // coalesced 4B
        fv[d] = fmaf(v.x, xr[ip & 255], fv[d]);
        fv[d] = fmaf(v.y, xr[(ip >> 8) & 255], fv[d]);
        fv[d] = fmaf(v.z, xr[(ip >> 16) & 255], fv[d]);
        fv[d] = fmaf(v.w, xr[ip >> 24], fv[d]);
      }
    }
  }

  float t012[8], t345[8];
  {
    float g0[DEPTH], g1[DEPTH];
#pragma unroll
    for (int d = 0; d < DEPTH; ++d) {
      float tl = (fv[d] - thr[n * DEPTH + d]) * expf(-ltemp[n * DEPTH + d]);
      float gg = fminf(fmaxf(0.5f * tl + 0.5f, 0.0f), 1.0f);  // sparsemoid
      g0[d] = gg;         // leaf bit 0 -> sparsemoid(+tl)
      g1[d] = 1.0f - gg;  // leaf bit 1 -> sparsemoid(-tl)
    }
#pragma unroll
    for (int c = 0; c < 8; ++c) {
      t012[c] = ((c & 1) ? g1[0] : g0[0]) * ((c & 2) ? g1[1] : g0[1]) *
                ((c & 4) ? g1[2] : g0[2]);
      t345[c] = ((c & 1) ? g1[3] : g0[3]) * ((c & 2) ? g1[4] : g0[4]) *
                ((c & 4) ? g1[5] : g0[5]);
    }
  }

  float o0 = 0.0f, o1 = 0.0f, o2 = 0.0f;
#pragma unroll
  for (int c = 0; c < NL; ++c) {
    float p = t012[c & 7] * t345[c >> 3];
    o0 = fmaf(p, rsp[0][c][nloc], o0);  // lane-stride 1: conflict-free
    o1 = fmaf(p, rsp[1][c][nloc], o1);
    o2 = fmaf(p, rsp[2][c][nloc], o2);
  }

  float* op = out + ((size_t)b * NT + n) * UNITS;
  op[0] = o0; op[1] = o1; op[2] = o2;
}

extern "C" void kernel_launch(void* const* d_in, const int* in_sizes, int n_in,
                              void* d_out, int out_size, void* d_ws, size_t ws_size,
                              hipStream_t stream) {
  const float* x    = (const float*)d_in[0];  // (512, 256)
  const float* fsl  = (const float*)d_in[1];  // (256, 512, 6)
  const float* thr  = (const float*)d_in[2];  // (512, 6)
  const float* lt   = (const float*)d_in[3];  // (512, 6)
  const float* resp = (const float*)d_in[4];  // (512, 3, 64)
  float* out = (float*)d_out;                 // (512, 512, 3)

  float* ws = (float*)d_ws;
  float4*       val4 = (float4*)ws;                     //  98304 f
  unsigned int* idx4 = (unsigned int*)(ws + 98304);     //  24576 f
  int*          cnt  = (int*)(ws + 122880);             //   3072 f

  k_sparse<<<COLS / 16, 512, 0, stream>>>(fsl, val4, idx4, cnt);
  k_forest5<<<1024, 256, 0, stream>>>(x, val4, idx4, cnt, thr, lt, resp, out);
}

// Round 6
// 85.837 us; speedup vs baseline: 1.1526x; 1.1526x over previous
//
#include <hip/hip_runtime.h>
#include <hip/hip_bf16.h>

#define BATCH 512
#define DIM 256
#define NT 512
#define DEPTH 6
#define UNITS 3
#define NL 64
#define COLS (NT * DEPTH)  // 3072
#define KMAX 32            // padded sparse entries per column (zero-filled)

// ws layout (float offsets):
//   val4  [DEPTH][8][NT] float4        0 .. 98304    packed sparse values
//   idx4  [DEPTH][8][NT] uint      98304 .. 122880   packed indices (4x u8)
//   respB [NL][NT] uint2          122880 .. 188416   bf16 response (u0|u1<<16, u2)
//   pth   [DEPTH][NT]             188416 .. 191488   thresholds [d][n]
//   pet   [DEPTH][NT]             191488 .. 194560   exp(-log_temp) [d][n]

__device__ __forceinline__ unsigned short f2bf(float f) {  // RNE f32->bf16
  unsigned int u = __float_as_uint(f);
  return (unsigned short)((u + 0x7fffu + ((u >> 16) & 1u)) >> 16);
}

// ---- Kernel 1: sparsemax + all packing ------------------------------------
// blocks 0..383  : sparsemax, 8 cols/block (1 col per wave)
// blocks 384..391: response -> bf16 respB[c][n] (64 trees/block, LDS transpose)
// blocks 392..393: thr/exp(-ltemp) -> [d][n]
__global__ __launch_bounds__(512) void k_prep6(
    const float* __restrict__ logits, const float* __restrict__ resp,
    const float* __restrict__ thr, const float* __restrict__ ltemp,
    float4* __restrict__ val4, unsigned int* __restrict__ idx4,
    uint2* __restrict__ respB, float* __restrict__ pth,
    float* __restrict__ pet) {
  const int bid = blockIdx.x, tid = threadIdx.x;
  __shared__ float tile[8][260];     // sparsemax branch
  __shared__ float lds[64 * 196];    // resp-pack branch

  if (bid < 384) {
    const int c0 = bid * 8;
#pragma unroll
    for (int it = 0; it < 4; ++it) {
      int e = it * 512 + tid;  // 0..2047
      int r = e >> 3, c = e & 7;
      tile[c][r] = logits[r * COLS + c0 + c];
    }
    __syncthreads();

    const int wv = tid >> 6, lane = tid & 63;
    const int col = c0 + wv;  // col = n*DEPTH + d
    const int n = col / DEPTH, d = col % DEPTH;

    float z[4];
#pragma unroll
    for (int j = 0; j < 4; ++j) z[j] = tile[wv][j * 64 + lane];

    float m = fmaxf(fmaxf(z[0], z[1]), fmaxf(z[2], z[3]));
#pragma unroll
    for (int o = 32; o > 0; o >>= 1) m = fmaxf(m, __shfl_xor(m, o, 64));

    // Newton on g(tau)=sum relu(z-tau)-1: convex piecewise-linear; from
    // tau0=max-1 (g>=0) monotone convergence, exact in final segment.
    float tau = m - 1.0f;
    for (int itn = 0; itn < 16; ++itn) {
      float s = 0.0f, k = 0.0f;
#pragma unroll
      for (int j = 0; j < 4; ++j) {
        float dd = z[j] - tau;
        if (dd > 0.0f) { s += dd; k += 1.0f; }
      }
#pragma unroll
      for (int o = 32; o > 0; o >>= 1) {
        s += __shfl_xor(s, o, 64);
        k += __shfl_xor(k, o, 64);
      }
      float delta = (s - 1.0f) / k;  // k>=1 always (tau < max)
      tau += delta;
      if (fabsf(delta) < 1e-7f) break;  // wave-uniform
    }

    // compact nonzeros into SoA groups of 4; zero-pad so consumer can run
    // a static KMAX loop (order-free: consumer sums)
    float* vbase = (float*)val4;
    unsigned char* ibase = (unsigned char*)idx4;
    int base = 0;
#pragma unroll
    for (int j = 0; j < 4; ++j) {
      bool nz = z[j] > tau;
      unsigned long long mk = __ballot(nz);
      int pos = base + __popcll(mk & ((1ull << lane) - 1ull));
      if (nz && pos < KMAX) {
        int slot = ((d * 8 + (pos >> 2)) * NT + n) * 4 + (pos & 3);
        vbase[slot] = z[j] - tau;
        ibase[slot] = (unsigned char)(j * 64 + lane);
      }
      base += __popcll(mk);
    }
    const int cc = min(base, KMAX);
    if (lane >= cc && lane < KMAX) {
      int slot = ((d * 8 + (lane >> 2)) * NT + n) * 4 + (lane & 3);
      vbase[slot] = 0.0f;
      ibase[slot] = 0;
    }
  } else if (bid < 392) {
    // response pack: 64 trees per block
    const int n0 = (bid - 384) * 64;
    const float4* r4 = (const float4*)(resp + n0 * 192);
#pragma unroll
    for (int k = 0; k < 6; ++k) {
      int f4 = k * 512 + tid;  // 0..3071
      float4 v = r4[f4];
      int nl = f4 / 48, rem = (f4 % 48) * 4;
      float* p = &lds[nl * 196 + rem];
      p[0] = v.x; p[1] = v.y; p[2] = v.z; p[3] = v.w;
    }
    __syncthreads();
#pragma unroll
    for (int k = 0; k < 8; ++k) {
      int s = k * 512 + tid;  // 0..4095
      int c = s >> 6, nl = s & 63;
      unsigned int b0 = f2bf(lds[nl * 196 + 0 * 64 + c]);
      unsigned int b1 = f2bf(lds[nl * 196 + 1 * 64 + c]);
      unsigned int b2 = f2bf(lds[nl * 196 + 2 * 64 + c]);
      respB[c * NT + n0 + nl] = make_uint2(b0 | (b1 << 16), b2);
    }
  } else {
    int i = (bid - 392) * 512 + tid;  // 0..1023
#pragma unroll
    for (int k = 0; k < 3; ++k) {
      int idx = k * 1024 + i;  // 0..3071
      int n = idx / DEPTH, d = idx % DEPTH;
      pth[d * NT + n] = thr[idx];
      pet[d * NT + n] = expf(-ltemp[idx]);
    }
  }
}

// ---- Kernel 2: sparse fv -> gates -> leaves -> output ---------------------
// 512 blocks x 256 thr: 64 trees x 8 rows/block, 2 rows/thread (4 wave-grps).
// Static fully-unrolled gather (zero-padded slots), no cnt/branches.
// blockIdx&7 = tree-tile -> XCD round-robin keeps val4/idx4/respB panels
// L2-local. LDS = 8KB only -> no occupancy cap.
__global__ __launch_bounds__(256) void k_forest6(
    const float* __restrict__ x, const float4* __restrict__ val4,
    const unsigned int* __restrict__ idx4, const float* __restrict__ pth,
    const float* __restrict__ pet, const uint2* __restrict__ respB,
    float* __restrict__ out) {
  const int tid = threadIdx.x;
  const int nloc = tid & 63, bg = tid >> 6;
  const int tt = blockIdx.x & 7, bt = blockIdx.x >> 3;
  const int n = tt * 64 + nloc;
  const int b0 = bt * 8;

  __shared__ float xl[8 * DIM];
#pragma unroll
  for (int k = 0; k < 8; ++k) xl[k * 256 + tid] = x[b0 * DIM + k * 256 + tid];
  __syncthreads();

  const float* xr0 = &xl[(bg * 2 + 0) * DIM];
  const float* xr1 = &xl[(bg * 2 + 1) * DIM];

  float fv0[DEPTH], fv1[DEPTH];
#pragma unroll
  for (int d = 0; d < DEPTH; ++d) { fv0[d] = 0.0f; fv1[d] = 0.0f; }

#pragma unroll
  for (int d = 0; d < DEPTH; ++d) {
#pragma unroll
    for (int jq = 0; jq < 8; ++jq) {
      float4 v = val4[(d * 8 + jq) * NT + n];           // coalesced 16B
      unsigned int ip = idx4[(d * 8 + jq) * NT + n];    // coalesced 4B
      int i0 = ip & 255, i1 = (ip >> 8) & 255;
      int i2 = (ip >> 16) & 255, i3 = ip >> 24;
      fv0[d] = fmaf(v.x, xr0[i0], fv0[d]); fv1[d] = fmaf(v.x, xr1[i0], fv1[d]);
      fv0[d] = fmaf(v.y, xr0[i1], fv0[d]); fv1[d] = fmaf(v.y, xr1[i1], fv1[d]);
      fv0[d] = fmaf(v.z, xr0[i2], fv0[d]); fv1[d] = fmaf(v.z, xr1[i2], fv1[d]);
      fv0[d] = fmaf(v.w, xr0[i3], fv0[d]); fv1[d] = fmaf(v.w, xr1[i3], fv1[d]);
    }
  }

  float t012[2][8], t345[2][8];
#pragma unroll
  for (int r = 0; r < 2; ++r) {
    float g0[DEPTH], g1[DEPTH];
#pragma unroll
    for (int d = 0; d < DEPTH; ++d) {
      float av = r ? fv1[d] : fv0[d];
      float tl = (av - pth[d * NT + n]) * pet[d * NT + n];  // coalesced
      float gg = fminf(fmaxf(0.5f * tl + 0.5f, 0.0f), 1.0f);  // sparsemoid
      g0[d] = gg;         // leaf bit 0 -> sparsemoid(+tl)
      g1[d] = 1.0f - gg;  // leaf bit 1 -> sparsemoid(-tl)
    }
#pragma unroll
    for (int c = 0; c < 8; ++c) {
      t012[r][c] = ((c & 1) ? g1[0] : g0[0]) * ((c & 2) ? g1[1] : g0[1]) *
                   ((c & 4) ? g1[2] : g0[2]);
      t345[r][c] = ((c & 1) ? g1[3] : g0[3]) * ((c & 2) ? g1[4] : g0[4]) *
                   ((c & 4) ? g1[5] : g0[5]);
    }
  }

  float o00 = 0, o01 = 0, o02 = 0, o10 = 0, o11 = 0, o12 = 0;
#pragma unroll
  for (int c = 0; c < NL; ++c) {
    uint2 rb = respB[c * NT + n];  // coalesced 8B
    float r0 = __uint_as_float(rb.x << 16);
    float r1 = __uint_as_float(rb.x & 0xffff0000u);
    float r2 = __uint_as_float(rb.y << 16);
    float p0 = t012[0][c & 7] * t345[0][c >> 3];
    float p1 = t012[1][c & 7] * t345[1][c >> 3];
    o00 = fmaf(p0, r0, o00); o01 = fmaf(p0, r1, o01); o02 = fmaf(p0, r2, o02);
    o10 = fmaf(p1, r0, o10); o11 = fmaf(p1, r1, o11); o12 = fmaf(p1, r2, o12);
  }

  const int ba = b0 + bg * 2, bb = ba + 1;
  float* oa = out + ((size_t)ba * NT + n) * UNITS;
  float* ob = out + ((size_t)bb * NT + n) * UNITS;
  oa[0] = o00; oa[1] = o01; oa[2] = o02;
  ob[0] = o10; ob[1] = o11; ob[2] = o12;
}

extern "C" void kernel_launch(void* const* d_in, const int* in_sizes, int n_in,
                              void* d_out, int out_size, void* d_ws, size_t ws_size,
                              hipStream_t stream) {
  const float* x    = (const float*)d_in[0];  // (512, 256)
  const float* fsl  = (const float*)d_in[1];  // (256, 512, 6)
  const float* thr  = (const float*)d_in[2];  // (512, 6)
  const float* lt   = (const float*)d_in[3];  // (512, 6)
  const float* resp = (const float*)d_in[4];  // (512, 3, 64)
  float* out = (float*)d_out;                 // (512, 512, 3)

  float* ws = (float*)d_ws;
  float4*       val4  = (float4*)ws;                 //      0 ..  98304 f
  unsigned int* idx4  = (unsigned int*)(ws + 98304); //  98304 .. 122880 f
  uint2*        respB = (uint2*)(ws + 122880);       // 122880 .. 188416 f
  float*        pth   = ws + 188416;                 // 188416 .. 191488 f
  float*        pet   = ws + 191488;                 // 191488 .. 194560 f

  k_prep6<<<394, 512, 0, stream>>>(fsl, resp, thr, lt, val4, idx4, respB, pth, pet);
  k_forest6<<<512, 256, 0, stream>>>(x, val4, idx4, pth, pet, respB, out);
}